// Round 1
// baseline (730.367 us; speedup 1.0000x reference)
//
#include <hip/hip_runtime.h>
#include <hip/hip_fp16.h>
#include <math.h>

#define BB 8
#define HH 384
#define WW 768
#define HW (HH * WW)
#define NPIX (BB * HW)

#define TX 64
#define TY 16
#define HX (TX + 6)      // 70
#define HY (TY + 6)      // 22
#define LSTR 72          // LDS row stride in Pair4 elements
#define TILES_X (WW / TX)            // 12
#define TILES_Y (HH / TY)            // 24
#define NTILE (TILES_X * TILES_Y)    // 288 per image
#define GRID (NTILE * BB)            // 2304

// Pair-symmetric census enumeration region: left endpoints q with
// rows -3..15 (19) x cols -3..66 (70). Offsets are the 24 canonical
// half-offsets {(0,1..3)} u {(1..3, -3..3)}; g(q,q+o) == g(q+o,q).
#define QROWS 19
#define QCOLS 70
#define NQ (QROWS * QCOLS)   // 1330

// ---------- exact bilinear (feeds binary occ -> must stay bit-stable) ----------
struct Bil { int x0, x1, y0, y1; float wx, wy; };

__device__ __forceinline__ Bil bilin_setup(float fx, float fy, int x, int y) {
    Bil s;
    float gx = fminf(fmaxf(fx + (float)x, 0.0f), (float)(WW - 1));
    float gy = fminf(fmaxf(fy + (float)y, 0.0f), (float)(HH - 1));
    float x0f = floorf(gx), y0f = floorf(gy);
    s.wx = gx - x0f;
    s.wy = gy - y0f;
    s.x0 = (int)x0f;
    s.y0 = (int)y0f;
    s.x1 = min(s.x0 + 1, WW - 1);
    s.y1 = min(s.y0 + 1, HH - 1);
    return s;
}

__device__ __forceinline__ float bilin(const float* __restrict__ pl, const Bil& s) {
    float v00 = pl[s.y0 * WW + s.x0];
    float v01 = pl[s.y0 * WW + s.x1];
    float v10 = pl[s.y1 * WW + s.x0];
    float v11 = pl[s.y1 * WW + s.x1];
    float iwx = 1.0f - s.wx, iwy = 1.0f - s.wy;
    return v00 * iwx * iwy + v01 * s.wx * iwy + v10 * iwx * s.wy + v11 * s.wx * s.wy;
}

// ---------- fast bilinear (image gathers; loss-tolerant) ----------
struct FBil { int off; float wx, wy; };

__device__ __forceinline__ FBil fast_setup(float fx, float fy, int x, int y) {
    FBil s;
    float gx = fminf(fmaxf(fx + (float)x, 0.0f), (float)(WW - 1));
    float gy = fminf(fmaxf(fy + (float)y, 0.0f), (float)(HH - 1));
    int x0 = min((int)floorf(gx), WW - 2);
    int y0 = min((int)floorf(gy), HH - 2);
    s.wx = gx - (float)x0;
    s.wy = gy - (float)y0;
    s.off = y0 * WW + x0;
    return s;
}

__device__ __forceinline__ float fbil(const float* __restrict__ pl, const FBil& s) {
    const float* q = pl + s.off;
    float v00 = q[0], v01 = q[1], v10 = q[WW], v11 = q[WW + 1];
    float top = fmaf(s.wx, v01 - v00, v00);
    float bot = fmaf(s.wx, v11 - v10, v10);
    return fmaf(s.wy, bot - top, top);
}

__device__ __forceinline__ float gray255(float r, float g, float b) {
    return (0.2989f * r + 0.587f * g + 0.114f * b) * 255.0f;
}

__device__ __forceinline__ float robust04(float a) {
    // pow(|a| + 0.01, 0.4) via HW log2/exp2 (arg always > 0)
    float v = fabsf(a) + 0.01f;
    return __builtin_amdgcn_exp2f(0.4f * __builtin_amdgcn_logf(v));
}

struct __align__(8) Pair4 {
    __half2 fw;   // (inten1, inten2w) — forward census pair
    __half2 bw;   // (inten2, inten1w) — backward census pair
};

// pacc layout per block: [pf, pb, mf, mb, cf, cb]
__global__ __launch_bounds__(256) void fused_kernel(
        const float* __restrict__ img1, const float* __restrict__ img2,
        const float* __restrict__ ffw, const float* __restrict__ fbw,
        float* __restrict__ pacc, float* __restrict__ occ_out) {
    __shared__ Pair4 TILE[HY][LSTR];      // 22*72*8 = 12.7 KB
    __shared__ float ACC[TY][TX][2];      // pair-census accumulators (fw,bw), 8 KB
    __shared__ uchar2 MASKB[TY][TX];      // (mf, mb) as bytes, 2 KB
    __shared__ float red[4][6];

    // XCD swizzle: under round-robin dispatch, XCD k gets image k's 288 tiles.
    const int img = blockIdx.x & 7;
    const int t = blockIdx.x >> 3;
    const int tyile = t / TILES_X;
    const int txile = t - tyile * TILES_X;
    const int gx0 = txile * TX - 3;
    const int gy0 = tyile * TY - 3;

    const float* i1 = img1 + img * 3 * HW;
    const float* i2 = img2 + img * 3 * HW;
    const float* f1 = ffw + img * 2 * HW;
    const float* f2 = fbw + img * 2 * HW;

    // zero the census accumulator field (covered by the phase-1 barrier)
    {
        float* az = &ACC[0][0][0];
        for (int i = threadIdx.x; i < TY * TX * 2; i += 256) az[i] = 0.0f;
    }

    float s_pf = 0.f, s_pb = 0.f, s_mf = 0.f, s_mb = 0.f;

    // ---- Phase 1: build packed f16 intensity planes (tile + halo) in LDS;
    //      occ/masks/photo for interior pixels along the way. ----
    for (int i = threadIdx.x; i < HX * HY; i += 256) {
        int ly = i / HX;
        int lx = i - ly * HX;
        int gx = gx0 + lx;
        int gy = gy0 + ly;
        bool inimg = (gx >= 0) & (gx < WW) & (gy >= 0) & (gy < HH);
        float v1 = 0.f, v2 = 0.f, v1w = 0.f, v2w = 0.f;
        if (inimg) {
            int p = gy * WW + gx;
            float fx = f1[p], fy = f1[HW + p];
            float bx = f2[p], by = f2[HW + p];
            float a0 = i1[p], a1 = i1[HW + p], a2 = i1[2 * HW + p];
            float c0 = i2[p], c1 = i2[HW + p], c2 = i2[2 * HW + p];

            // image gathers: fast shared-base path (feeds losses only)
            FBil qf = fast_setup(fx, fy, gx, gy);
            FBil qb = fast_setup(bx, by, gx, gy);
            float w20 = fbil(i2, qf);
            float w21 = fbil(i2 + HW, qf);
            float w22 = fbil(i2 + 2 * HW, qf);
            float w10 = fbil(i1, qb);
            float w11 = fbil(i1 + HW, qb);
            float w12 = fbil(i1 + 2 * HW, qb);

            v1 = gray255(a0, a1, a2);
            v2 = gray255(c0, c1, c2);
            v2w = gray255(w20, w21, w22);
            v1w = gray255(w10, w11, w12);

            bool interior = (lx >= 3) & (lx < 3 + TX) & (ly >= 3) & (ly < 3 + TY);
            if (interior) {
                // flow gathers: exact path (feeds binary occ)
                Bil sf = bilin_setup(fx, fy, gx, gy);
                Bil sb = bilin_setup(bx, by, gx, gy);
                float wbx = bilin(f2, sf), wby = bilin(f2 + HW, sf);
                float wfx = bilin(f1, sb), wfy = bilin(f1 + HW, sb);

                float dfx = fx + wbx, dfy = fy + wby;
                float magf = dfx * dfx + dfy * dfy;
                float fmf = fx * fx + fy * fy + wbx * wbx + wby * wby;
                float occf = (magf > 0.01f * fmf + 0.5f) ? 1.0f : 0.0f;
                float mf = 1.0f - occf;

                float dbx = bx + wfx, dby = by + wfy;
                float magb = dbx * dbx + dby * dby;
                float fmb = bx * bx + by * by + wfx * wfx + wfy * wfy;
                float occb = (magb > 0.01f * fmb + 0.5f) ? 1.0f : 0.0f;
                float mb = 1.0f - occb;

                MASKB[ly - 3][lx - 3] = make_uchar2((unsigned char)mf, (unsigned char)mb);
                occ_out[img * HW + p] = occf;

                s_pf += (robust04(a0 - w20) + robust04(a1 - w21) + robust04(a2 - w22)) * mf;
                s_pb += (robust04(c0 - w10) + robust04(c1 - w11) + robust04(c2 - w12)) * mb;
                s_mf += mf;
                s_mb += mb;
            }
        }
        Pair4 pr;
        pr.fw = __floats2half2_rn(v1, v2w);
        pr.bw = __floats2half2_rn(v2, v1w);
        TILE[ly][lx] = pr;
    }
    __syncthreads();

    // ---- Phase 2: pair-symmetric census. f(u)=u/sqrt(0.81+u^2) is odd, so
    //      the per-tap contribution d2/(0.1+d2) is IDENTICAL at both endpoints
    //      of a pixel pair {q, q+o}: compute each pair once (24 canonical
    //      offsets instead of 49 taps) and scatter to both endpoints.
    //      Left endpoint accumulates in registers (1 atomic pair per q);
    //      right endpoint via ds_add_f32 into ACC (lane-distinct addresses,
    //      conflict-free; LDS pipe, doesn't block VALU).
    //      Trans reduction: dist = s^2*(u1^2*a2 + u2^2*a1) - 2*u1*u2*s with a
    //      SINGLE s = rsq(a1*a2) per stream, plus one shared rcp for both
    //      streams: 3 trans per pair-eval vs 6 in the tap formulation. ----
    {
        constexpr int ODY[24] = {0,0,0, 1,1,1,1,1,1,1, 2,2,2,2,2,2,2, 3,3,3,3,3,3,3};
        constexpr int ODX[24] = {1,2,3, -3,-2,-1,0,1,2,3, -3,-2,-1,0,1,2,3, -3,-2,-1,0,1,2,3};
#pragma unroll 1
        for (int it = 0; it < 6; ++it) {
            int i = threadIdx.x + it * 256;
            if (i < NQ) {
                int qr = i / QCOLS - 3;
                int qc = i - (qr + 3) * QCOLS - 3;
                const Pair4* base = &TILE[3 + qr][3 + qc];
                Pair4 C = *base;
                float2 cf = __half22float2(C.fw);
                float2 cb = __half22float2(C.bw);
                bool qin = ((unsigned)qr < 16u) && ((unsigned)qc < 64u);
                // precomputed endpoint validity per row/col delta
                bool rvv[4], cvv[7];
#pragma unroll
                for (int d = 0; d < 4; ++d) rvv[d] = ((unsigned)(qr + d) < 16u);
#pragma unroll
                for (int d = 0; d < 7; ++d) cvv[d] = ((unsigned)(qc + d - 3) < 64u);
                float* abase = &ACC[0][0][0] + (qr * TX + qc) * 2;
                float laccf = 0.f, laccb = 0.f;
#pragma unroll
                for (int k = 0; k < 24; ++k) {
                    Pair4 V = base[ODY[k] * LSTR + ODX[k]];
                    float2 vf = __half22float2(V.fw);
                    float2 vb = __half22float2(V.bw);
                    // stream fw
                    float u1 = vf.x - cf.x, u2 = vf.y - cf.y;
                    float q1 = u1 * u1, q2 = u2 * u2;
                    float a1 = q1 + 0.81f, a2 = q2 + 0.81f;
                    float s  = __builtin_amdgcn_rsqf(a1 * a2);
                    float df = fmaf(s * s, fmaf(q1, a2, q2 * a1), -2.0f * ((u1 * u2) * s));
                    // stream bw
                    float w1 = vb.x - cb.x, w2 = vb.y - cb.y;
                    float p1 = w1 * w1, p2 = w2 * w2;
                    float b1 = p1 + 0.81f, b2 = p2 + 0.81f;
                    float tt = __builtin_amdgcn_rsqf(b1 * b2);
                    float db = fmaf(tt * tt, fmaf(p1, b2, p2 * b1), -2.0f * ((w1 * w2) * tt));
                    // shared rcp across streams
                    float denf = 0.1f + df, denb = 0.1f + db;
                    float rr = __builtin_amdgcn_rcpf(denf * denb);
                    float gf = df * (denb * rr);
                    float gb = db * (denf * rr);
                    laccf += gf; laccb += gb;
                    if (rvv[ODY[k]] && cvv[ODX[k] + 3]) {
                        atomicAdd(abase + (ODY[k] * TX + ODX[k]) * 2, gf);
                        atomicAdd(abase + (ODY[k] * TX + ODX[k]) * 2 + 1, gb);
                    }
                }
                if (qin) {
                    atomicAdd(abase, laccf);
                    atomicAdd(abase + 1, laccb);
                }
            }
        }
    }
    __syncthreads();

    // ---- Epilogue: robust04(dist_sum) * mask over interior pixels. ----
    float s_cf = 0.f, s_cb = 0.f;
    for (int i = threadIdx.x; i < TY * TX; i += 256) {
        int r = i >> 6, c = i & 63;
        uchar2 mm = MASKB[r][c];
        s_cf += robust04(ACC[r][c][0]) * (float)mm.x;
        s_cb += robust04(ACC[r][c][1]) * (float)mm.y;
    }

    // ---- Reduce 6 partials across the block. ----
    const int band = threadIdx.x >> 6;
    for (int o = 32; o > 0; o >>= 1) {
        s_pf += __shfl_down(s_pf, o, 64);
        s_pb += __shfl_down(s_pb, o, 64);
        s_mf += __shfl_down(s_mf, o, 64);
        s_mb += __shfl_down(s_mb, o, 64);
        s_cf += __shfl_down(s_cf, o, 64);
        s_cb += __shfl_down(s_cb, o, 64);
    }
    if ((threadIdx.x & 63) == 0) {
        red[band][0] = s_pf; red[band][1] = s_pb;
        red[band][2] = s_mf; red[band][3] = s_mb;
        red[band][4] = s_cf; red[band][5] = s_cb;
    }
    __syncthreads();
    if (threadIdx.x == 0) {
        float r0 = 0.f, r1 = 0.f, r2 = 0.f, r3 = 0.f, r4 = 0.f, r5 = 0.f;
        for (int i = 0; i < 4; ++i) {
            r0 += red[i][0]; r1 += red[i][1]; r2 += red[i][2];
            r3 += red[i][3]; r4 += red[i][4]; r5 += red[i][5];
        }
        float* o = pacc + blockIdx.x * 6;
        o[0] = r0; o[1] = r1; o[2] = r2; o[3] = r3; o[4] = r4; o[5] = r5;
    }
}

__global__ __launch_bounds__(256) void finalize_kernel(
        const float* __restrict__ pacc, float* __restrict__ out) {
    float s0 = 0.f, s1 = 0.f, s2 = 0.f, s3 = 0.f, s4 = 0.f, s5 = 0.f;
    for (int i = threadIdx.x; i < GRID; i += 256) {
        const float* o = pacc + i * 6;
        s0 += o[0]; s1 += o[1]; s2 += o[2];
        s3 += o[3]; s4 += o[4]; s5 += o[5];
    }
    for (int o = 32; o > 0; o >>= 1) {
        s0 += __shfl_down(s0, o, 64);
        s1 += __shfl_down(s1, o, 64);
        s2 += __shfl_down(s2, o, 64);
        s3 += __shfl_down(s3, o, 64);
        s4 += __shfl_down(s4, o, 64);
        s5 += __shfl_down(s5, o, 64);
    }
    __shared__ float red[4][6];
    int w = threadIdx.x >> 6;
    if ((threadIdx.x & 63) == 0) {
        red[w][0] = s0; red[w][1] = s1; red[w][2] = s2;
        red[w][3] = s3; red[w][4] = s4; red[w][5] = s5;
    }
    __syncthreads();
    if (threadIdx.x == 0) {
        float t0 = 0.f, t1 = 0.f, t2 = 0.f, t3 = 0.f, t4 = 0.f, t5 = 0.f;
        for (int i = 0; i < 4; ++i) {
            t0 += red[i][0]; t1 += red[i][1]; t2 += red[i][2];
            t3 += red[i][3]; t4 += red[i][4]; t5 += red[i][5];
        }
        float denf = t2 * 2.0f + 1e-6f;
        float denb = t3 * 2.0f + 1e-6f;
        float photo = t0 / denf + t1 / denb;
        float cens = t4 / denf + t5 / denb;
        out[0] = photo + cens;
        out[1] = photo;
        out[2] = cens;
    }
}

extern "C" void kernel_launch(void* const* d_in, const int* in_sizes, int n_in,
                              void* d_out, int out_size, void* d_ws, size_t ws_size,
                              hipStream_t stream) {
    const float* img1 = (const float*)d_in[0];
    const float* img2 = (const float*)d_in[1];
    const float* ffw = (const float*)d_in[2];
    const float* fbw = (const float*)d_in[3];
    float* out = (float*)d_out;
    float* pacc = (float*)d_ws;   // GRID*6 floats

    fused_kernel<<<GRID, 256, 0, stream>>>(img1, img2, ffw, fbw, pacc, out + 3);
    finalize_kernel<<<1, 256, 0, stream>>>(pacc, out);
}

// Round 2
// 218.684 us; speedup vs baseline: 3.3398x; 3.3398x over previous
//
#include <hip/hip_runtime.h>
#include <hip/hip_fp16.h>
#include <math.h>

#define BB 8
#define HH 384
#define WW 768
#define HW (HH * WW)

#define NT 512           // threads per block
#define TX 64
#define TY 16
#define HX (TX + 6)      // 70
#define HY (TY + 6)      // 22
#define LSTR 73          // LDS row stride in float4 (73*16B = 1168B, bank-offset 4/row)
#define TILES_X (WW / TX)            // 12
#define TILES_Y (HH / TY)            // 24
#define NTILE (TILES_X * TILES_Y)    // 288 per image
#define GRID (NTILE * BB)            // 2304

// ---------- exact bilinear (feeds binary occ -> must stay bit-stable) ----------
struct Bil { int x0, x1, y0, y1; float wx, wy; };

__device__ __forceinline__ Bil bilin_setup(float fx, float fy, int x, int y) {
    Bil s;
    float gx = fminf(fmaxf(fx + (float)x, 0.0f), (float)(WW - 1));
    float gy = fminf(fmaxf(fy + (float)y, 0.0f), (float)(HH - 1));
    float x0f = floorf(gx), y0f = floorf(gy);
    s.wx = gx - x0f;
    s.wy = gy - y0f;
    s.x0 = (int)x0f;
    s.y0 = (int)y0f;
    s.x1 = min(s.x0 + 1, WW - 1);
    s.y1 = min(s.y0 + 1, HH - 1);
    return s;
}

__device__ __forceinline__ float bilin(const float* __restrict__ pl, const Bil& s) {
    float v00 = pl[s.y0 * WW + s.x0];
    float v01 = pl[s.y0 * WW + s.x1];
    float v10 = pl[s.y1 * WW + s.x0];
    float v11 = pl[s.y1 * WW + s.x1];
    float iwx = 1.0f - s.wx, iwy = 1.0f - s.wy;
    return v00 * iwx * iwy + v01 * s.wx * iwy + v10 * iwx * s.wy + v11 * s.wx * s.wy;
}

// ---------- fast bilinear (image gathers; loss-tolerant) ----------
struct FBil { int off; float wx, wy; };

__device__ __forceinline__ FBil fast_setup(float fx, float fy, int x, int y) {
    FBil s;
    float gx = fminf(fmaxf(fx + (float)x, 0.0f), (float)(WW - 1));
    float gy = fminf(fmaxf(fy + (float)y, 0.0f), (float)(HH - 1));
    int x0 = min((int)floorf(gx), WW - 2);
    int y0 = min((int)floorf(gy), HH - 2);
    s.wx = gx - (float)x0;
    s.wy = gy - (float)y0;
    s.off = y0 * WW + x0;
    return s;
}

__device__ __forceinline__ float fbil(const float* __restrict__ pl, const FBil& s) {
    const float* q = pl + s.off;
    float v00 = q[0], v01 = q[1], v10 = q[WW], v11 = q[WW + 1];
    float top = fmaf(s.wx, v01 - v00, v00);
    float bot = fmaf(s.wx, v11 - v10, v10);
    return fmaf(s.wy, bot - top, top);
}

__device__ __forceinline__ float gray255(float r, float g, float b) {
    return (0.2989f * r + 0.587f * g + 0.114f * b) * 255.0f;
}

__device__ __forceinline__ float robust04(float a) {
    // pow(|a| + 0.01, 0.4) via HW log2/exp2 (arg always > 0)
    float v = fabsf(a) + 0.01f;
    return __builtin_amdgcn_exp2f(0.4f * __builtin_amdgcn_logf(v));
}

// Census tap: dist contribution for both streams.
// f(u) = u/sqrt(0.81+u^2); d2 = (f(u1)-f(u2))^2 via single-rsq identity:
// d2 = s^2*(q1*a2 + q2*a1) - 2*u1*u2*s, s = rsq(a1*a2)   [validated round 1]
// then dsf += d2f/(0.1+d2f) with ONE rcp shared across fw/bw streams.
__device__ __forceinline__ void tap_eval(const float4 V, const float4 C,
                                         float& dsf, float& dsb) {
    float u1 = V.x - C.x, u2 = V.y - C.y;
    float q1 = u1 * u1, q2 = u2 * u2;
    float a1 = q1 + 0.81f, a2 = q2 + 0.81f;
    float sf = __builtin_amdgcn_rsqf(a1 * a2);
    float hf = fmaf(q1, a2, q2 * a1);
    float d2f = fmaf(sf * sf, hf, -2.0f * ((u1 * u2) * sf));

    float w1 = V.z - C.z, w2 = V.w - C.w;
    float p1 = w1 * w1, p2 = w2 * w2;
    float b1 = p1 + 0.81f, b2 = p2 + 0.81f;
    float sb = __builtin_amdgcn_rsqf(b1 * b2);
    float hb = fmaf(p1, b2, p2 * b1);
    float d2b = fmaf(sb * sb, hb, -2.0f * ((w1 * w2) * sb));

    float denf = 0.1f + d2f, denb = 0.1f + d2b;
    float rr = __builtin_amdgcn_rcpf(denf * denb);
    dsf = fmaf(d2f * denb, rr, dsf);
    dsb = fmaf(d2b * denf, rr, dsb);
}

// pacc layout per block: [pf, pb, mf, mb, cf, cb]
__global__ __launch_bounds__(NT) void fused_kernel(
        const float* __restrict__ img1, const float* __restrict__ img2,
        const float* __restrict__ ffw, const float* __restrict__ fbw,
        float* __restrict__ pacc, float* __restrict__ occ_out) {
    __shared__ float4 TILE[HY][LSTR];     // (i1, i2w, i2, i1w) per pixel, 25.7 KB
    __shared__ uchar2 MASKB[TY][TX];      // (mf, mb) as bytes, 2 KB
    __shared__ unsigned short WORK[TY * TX];  // live-pixel worklist, 2 KB
    __shared__ int wcnt[16];              // per-wave live counts (2 passes)
    __shared__ float red[8][6];

    // XCD swizzle: under round-robin dispatch, XCD k gets image k's 288 tiles.
    const int img = blockIdx.x & 7;
    const int t = blockIdx.x >> 3;
    const int tyile = t / TILES_X;
    const int txile = t - tyile * TILES_X;
    const int gx0 = txile * TX - 3;
    const int gy0 = tyile * TY - 3;

    const float* i1 = img1 + img * 3 * HW;
    const float* i2 = img2 + img * 3 * HW;
    const float* f1 = ffw + img * 2 * HW;
    const float* f2 = fbw + img * 2 * HW;

    float s_pf = 0.f, s_pb = 0.f, s_mf = 0.f, s_mb = 0.f;

    // ---- Phase 1: build f32 intensity planes (tile + halo) in LDS;
    //      occ/masks/photo for interior pixels along the way. ----
    for (int i = threadIdx.x; i < HX * HY; i += NT) {
        int ly = i / HX;
        int lx = i - ly * HX;
        int gx = gx0 + lx;
        int gy = gy0 + ly;
        bool inimg = (gx >= 0) & (gx < WW) & (gy >= 0) & (gy < HH);
        float v1 = 0.f, v2 = 0.f, v1w = 0.f, v2w = 0.f;
        if (inimg) {
            int p = gy * WW + gx;
            float fx = f1[p], fy = f1[HW + p];
            float bx = f2[p], by = f2[HW + p];
            float a0 = i1[p], a1 = i1[HW + p], a2 = i1[2 * HW + p];
            float c0 = i2[p], c1 = i2[HW + p], c2 = i2[2 * HW + p];

            // image gathers: fast shared-base path (feeds losses only)
            FBil qf = fast_setup(fx, fy, gx, gy);
            FBil qb = fast_setup(bx, by, gx, gy);
            float w20 = fbil(i2, qf);
            float w21 = fbil(i2 + HW, qf);
            float w22 = fbil(i2 + 2 * HW, qf);
            float w10 = fbil(i1, qb);
            float w11 = fbil(i1 + HW, qb);
            float w12 = fbil(i1 + 2 * HW, qb);

            v1 = gray255(a0, a1, a2);
            v2 = gray255(c0, c1, c2);
            v2w = gray255(w20, w21, w22);
            v1w = gray255(w10, w11, w12);

            bool interior = (lx >= 3) & (lx < 3 + TX) & (ly >= 3) & (ly < 3 + TY);
            if (interior) {
                // flow gathers: exact path (feeds binary occ)
                Bil sf = bilin_setup(fx, fy, gx, gy);
                Bil sb = bilin_setup(bx, by, gx, gy);
                float wbx = bilin(f2, sf), wby = bilin(f2 + HW, sf);
                float wfx = bilin(f1, sb), wfy = bilin(f1 + HW, sb);

                float dfx = fx + wbx, dfy = fy + wby;
                float magf = dfx * dfx + dfy * dfy;
                float fmf = fx * fx + fy * fy + wbx * wbx + wby * wby;
                float occf = (magf > 0.01f * fmf + 0.5f) ? 1.0f : 0.0f;
                float mf = 1.0f - occf;

                float dbx = bx + wfx, dby = by + wfy;
                float magb = dbx * dbx + dby * dby;
                float fmb = bx * bx + by * by + wfx * wfx + wfy * wfy;
                float occb = (magb > 0.01f * fmb + 0.5f) ? 1.0f : 0.0f;
                float mb = 1.0f - occb;

                MASKB[ly - 3][lx - 3] = make_uchar2((unsigned char)mf, (unsigned char)mb);
                occ_out[img * HW + p] = occf;

                s_pf += (robust04(a0 - w20) + robust04(a1 - w21) + robust04(a2 - w22)) * mf;
                s_pb += (robust04(c0 - w10) + robust04(c1 - w11) + robust04(c2 - w12)) * mb;
                s_mf += mf;
                s_mb += mb;
            }
        }
        TILE[ly][lx] = make_float4(v1, v2w, v2, v1w);
    }
    __syncthreads();

    // ---- Phase 2a: deterministic live-pixel compaction (no atomics).
    //      ~72-75% of pixels have mf=mb=0 (binary masks) and contribute
    //      exactly 0 to the census loss — skip them wave-coherently. ----
    const int lane = threadIdx.x & 63;
    const int wid = threadIdx.x >> 6;           // 0..7
    const unsigned long long lt = (1ull << lane) - 1ull;
    int ntot;
    {
        int pix0 = threadIdx.x;                 // 0..511
        int pix1 = threadIdx.x + NT;            // 512..1023
        uchar2 m0 = MASKB[pix0 >> 6][pix0 & 63];
        uchar2 m1 = MASKB[pix1 >> 6][pix1 & 63];
        bool l0 = (m0.x | m0.y) != 0;
        bool l1 = (m1.x | m1.y) != 0;
        unsigned long long b0 = __ballot(l0);
        unsigned long long b1 = __ballot(l1);
        if (lane == 0) {
            wcnt[wid] = __popcll(b0);
            wcnt[8 + wid] = __popcll(b1);
        }
        __syncthreads();
        int base0 = 0, base1 = 0;
        ntot = 0;
        for (int k = 0; k < 16; ++k) {
            int v = wcnt[k];
            if (k < wid) base0 += v;
            if (k < 8 + wid) base1 += v;
            ntot += v;
        }
        if (l0) WORK[base0 + __popcll(b0 & lt)] = (unsigned short)pix0;
        if (l1) WORK[base1 + __popcll(b1 & lt)] = (unsigned short)pix1;
        __syncthreads();
    }

    // ---- Phase 2b: 49-tap census over the worklist only. ----
    float s_cf = 0.f, s_cb = 0.f;
    for (int w = threadIdx.x; w < ntot; w += NT) {
        int pix = WORK[w];
        int r = pix >> 6, c = pix & 63;
        float4 C = TILE[3 + r][3 + c];
        float dsf = 0.f, dsb = 0.f;
#pragma unroll 1
        for (int dy = 0; dy < 7; ++dy) {
            const float4* prow = &TILE[r + dy][c];
#pragma unroll
            for (int dx = 0; dx < 7; ++dx) {
                // center tap (dy==3,dx==3) contributes exactly 0 — harmless
                tap_eval(prow[dx], C, dsf, dsb);
            }
        }
        uchar2 mm = MASKB[r][c];
        s_cf += robust04(dsf) * (float)mm.x;
        s_cb += robust04(dsb) * (float)mm.y;
    }

    // ---- Reduce 6 partials across the block (8 waves). ----
    for (int o = 32; o > 0; o >>= 1) {
        s_pf += __shfl_down(s_pf, o, 64);
        s_pb += __shfl_down(s_pb, o, 64);
        s_mf += __shfl_down(s_mf, o, 64);
        s_mb += __shfl_down(s_mb, o, 64);
        s_cf += __shfl_down(s_cf, o, 64);
        s_cb += __shfl_down(s_cb, o, 64);
    }
    if (lane == 0) {
        red[wid][0] = s_pf; red[wid][1] = s_pb;
        red[wid][2] = s_mf; red[wid][3] = s_mb;
        red[wid][4] = s_cf; red[wid][5] = s_cb;
    }
    __syncthreads();
    if (threadIdx.x == 0) {
        float r0 = 0.f, r1 = 0.f, r2 = 0.f, r3 = 0.f, r4 = 0.f, r5 = 0.f;
        for (int i = 0; i < 8; ++i) {
            r0 += red[i][0]; r1 += red[i][1]; r2 += red[i][2];
            r3 += red[i][3]; r4 += red[i][4]; r5 += red[i][5];
        }
        float* o = pacc + blockIdx.x * 6;
        o[0] = r0; o[1] = r1; o[2] = r2; o[3] = r3; o[4] = r4; o[5] = r5;
    }
}

__global__ __launch_bounds__(256) void finalize_kernel(
        const float* __restrict__ pacc, float* __restrict__ out) {
    float s0 = 0.f, s1 = 0.f, s2 = 0.f, s3 = 0.f, s4 = 0.f, s5 = 0.f;
    for (int i = threadIdx.x; i < GRID; i += 256) {
        const float* o = pacc + i * 6;
        s0 += o[0]; s1 += o[1]; s2 += o[2];
        s3 += o[3]; s4 += o[4]; s5 += o[5];
    }
    for (int o = 32; o > 0; o >>= 1) {
        s0 += __shfl_down(s0, o, 64);
        s1 += __shfl_down(s1, o, 64);
        s2 += __shfl_down(s2, o, 64);
        s3 += __shfl_down(s3, o, 64);
        s4 += __shfl_down(s4, o, 64);
        s5 += __shfl_down(s5, o, 64);
    }
    __shared__ float red[4][6];
    int w = threadIdx.x >> 6;
    if ((threadIdx.x & 63) == 0) {
        red[w][0] = s0; red[w][1] = s1; red[w][2] = s2;
        red[w][3] = s3; red[w][4] = s4; red[w][5] = s5;
    }
    __syncthreads();
    if (threadIdx.x == 0) {
        float t0 = 0.f, t1 = 0.f, t2 = 0.f, t3 = 0.f, t4 = 0.f, t5 = 0.f;
        for (int i = 0; i < 4; ++i) {
            t0 += red[i][0]; t1 += red[i][1]; t2 += red[i][2];
            t3 += red[i][3]; t4 += red[i][4]; t5 += red[i][5];
        }
        float denf = t2 * 2.0f + 1e-6f;
        float denb = t3 * 2.0f + 1e-6f;
        float photo = t0 / denf + t1 / denb;
        float cens = t4 / denf + t5 / denb;
        out[0] = photo + cens;
        out[1] = photo;
        out[2] = cens;
    }
}

extern "C" void kernel_launch(void* const* d_in, const int* in_sizes, int n_in,
                              void* d_out, int out_size, void* d_ws, size_t ws_size,
                              hipStream_t stream) {
    const float* img1 = (const float*)d_in[0];
    const float* img2 = (const float*)d_in[1];
    const float* ffw = (const float*)d_in[2];
    const float* fbw = (const float*)d_in[3];
    float* out = (float*)d_out;
    float* pacc = (float*)d_ws;   // GRID*6 floats

    fused_kernel<<<GRID, NT, 0, stream>>>(img1, img2, ffw, fbw, pacc, out + 3);
    finalize_kernel<<<1, 256, 0, stream>>>(pacc, out);
}